// Round 4
// baseline (543.632 us; speedup 1.0000x reference)
//
#include <hip/hip_runtime.h>

#define S_LEN  2048
#define BATCH  1024
#define NL     6
#define CH     16      // timesteps per chunk (x-prefetch granularity)
#define SKEW   2       // pipeline skew per layer (hides bpermute latency)
#define NSTEP  (S_LEN + SKEW * (NL - 1))   // 2058 real steps
#define NCHUNK ((NSTEP + CH - 1) / CH)     // 129 chunks (2064 steps)

__device__ __forceinline__ float fexp2(float x) { return __builtin_amdgcn_exp2f(x); }
__device__ __forceinline__ float frcp(float x)  { return __builtin_amdgcn_rcpf(x); }

// quad_perm DPP: xor1=[1,0,3,2]=0xB1, xor2=[2,3,0,1]=0x4E, xor3=[3,2,1,0]=0x1B
template <int CTRL>
__device__ __forceinline__ float dppf(float v) {
    return __int_as_float(__builtin_amdgcn_update_dpp(
        0, __float_as_int(v), CTRL, 0xF, 0xF, true));
}
__device__ __forceinline__ float bpermf(int addr, float v) {
    return __int_as_float(__builtin_amdgcn_ds_bpermute(addr, __float_as_int(v)));
}
__device__ __forceinline__ float sigf(float x)  { return frcp(1.0f + fexp2(x * -1.442695041f)); }
__device__ __forceinline__ float tanh_(float x) { return fmaf(2.0f, frcp(1.0f + fexp2(x * -2.885390082f)), -1.0f); }

// ONE wave carries the whole 6-layer pipeline for 2 batch elements.
// lane = L*8 + e*4 + j (L=layer 0..5; lanes 48-55 idle; lanes 56-63 feeders
// whose h register holds x[t]). Skew-2 pipeline: at global step n, layer L
// computes t = n - 2L, consuming h_{L-1}(t) that was produced at step n-2 and
// shipped through a 2-deep ds_bpermute queue -> LDS-pipe latency (~120cyc) is
// fully hidden behind one whole step. No barriers, no LDS buffers.
__global__ __launch_bounds__(64, 1) void lstm_wavepipe2(
    const float* __restrict__ x, const float* __restrict__ w_ih,
    const float* __restrict__ w_hh, const float* __restrict__ b_ih,
    const float* __restrict__ b_hh, const float* __restrict__ reg_w,
    const float* __restrict__ reg_b, float* __restrict__ out) {
    const int lane = threadIdx.x;
    const int L    = lane >> 3;
    const int e    = (lane >> 2) & 1;
    const int j    = lane & 3;
    const int b    = blockIdx.x * 2 + e;
    const int Lc   = (L < NL) ? L : NL - 1;      // clamp for safe weight loads
    const bool isFeeder = (lane >= 56);
    const bool isOut    = (L == 5) && (j == 0);

    // ---- weight preload, permuted so term m multiplies value of unit j^m ----
    float Wx[4][4], Wh[4][4], Gb[4];
#pragma unroll
    for (int g = 0; g < 4; ++g) {
        const int row = Lc * 16 + g * 4 + j;     // PyTorch gate order i,f,g,o
#pragma unroll
        for (int m = 0; m < 4; ++m) {
            Wx[g][m] = w_ih[row * 4 + (j ^ m)];
            Wh[g][m] = w_hh[row * 4 + (j ^ m)];
        }
        Gb[g] = b_ih[row] + b_hh[row];
    }
    const float regw = reg_w[j];
    const float regb = reg_b[0];
    const int bpaddr = ((lane >= 8) ? (lane - 8) : (lane + 56)) << 2;
    // after ++ at step n: tc = n - 2L; non-compute lanes never activate
    int tc = (L < NL) ? (-2 * L - 1) : -2100000000;

    const size_t xoff = (size_t)(b * 4 + j);     // x[t*4096 + 4b + j]
    float h = 0.0f, c = 0.0f;
    float xu[CH], xp[CH], su[CH];

    // ---- prime the 2-deep handoff queue (steps -2 and -1) ----
    float fh = isFeeder ? x[xoff] : 0.0f;                 // feeder h at "-2" = x[0]
    float q0 = bpermf(bpaddr, fh);
    fh = isFeeder ? x[4096 + xoff] : 0.0f;                // feeder h at "-1" = x[1]
    float q1 = bpermf(bpaddr, fh);
    h = isFeeder ? fh : 0.0f;

    // xu[u] holds x[cc*16 + u + 2]  (feeders publish 2 steps ahead)
#pragma unroll
    for (int u = 0; u < CH; ++u) {
        int t2 = u + 2; if (t2 > S_LEN - 1) t2 = S_LEN - 1;
        xu[u] = x[(size_t)t2 * 4096 + xoff];
    }

    for (int cc = 0; cc < NCHUNK; ++cc) {
        // ---- prefetch next chunk's x (lands during the 16 steps below) ----
#pragma unroll
        for (int u = 0; u < CH; ++u) {
            int t2 = (cc + 1) * CH + u + 2;
            if (t2 > S_LEN - 1) t2 = S_LEN - 1;
            xp[u] = x[(size_t)t2 * 4096 + xoff];
        }
        // ---- 16 pipeline steps ----
#pragma unroll
        for (int u = 0; u < CH; ++u) {
            ++tc;
            const float hup = q0;            // bperm issued 2 steps ago: ready
            q0 = q1;
            // x-side partials first (independent of this step's h-chain)
            const float xv1 = dppf<0xB1>(hup), xv2 = dppf<0x4E>(hup), xv3 = dppf<0x1B>(hup);
            float Gi = Gb[0], Gf = Gb[1], Gg = Gb[2], Go = Gb[3];
            Gi = fmaf(Wx[0][0], hup, Gi); Gf = fmaf(Wx[1][0], hup, Gf);
            Gg = fmaf(Wx[2][0], hup, Gg); Go = fmaf(Wx[3][0], hup, Go);
            Gi = fmaf(Wx[0][1], xv1, Gi); Gf = fmaf(Wx[1][1], xv1, Gf);
            Gg = fmaf(Wx[2][1], xv1, Gg); Go = fmaf(Wx[3][1], xv1, Go);
            Gi = fmaf(Wx[0][2], xv2, Gi); Gf = fmaf(Wx[1][2], xv2, Gf);
            Gg = fmaf(Wx[2][2], xv2, Gg); Go = fmaf(Wx[3][2], xv2, Go);
            Gi = fmaf(Wx[0][3], xv3, Gi); Gf = fmaf(Wx[1][3], xv3, Gf);
            Gg = fmaf(Wx[2][3], xv3, Gg); Go = fmaf(Wx[3][3], xv3, Go);
            // own-h terms (the true serial chain: 3 DPP + 4-deep FMA)
            const float hv1 = dppf<0xB1>(h), hv2 = dppf<0x4E>(h), hv3 = dppf<0x1B>(h);
            Gi = fmaf(Wh[0][0], h, Gi);   Gf = fmaf(Wh[1][0], h, Gf);
            Gg = fmaf(Wh[2][0], h, Gg);   Go = fmaf(Wh[3][0], h, Go);
            Gi = fmaf(Wh[0][1], hv1, Gi); Gf = fmaf(Wh[1][1], hv1, Gf);
            Gg = fmaf(Wh[2][1], hv1, Gg); Go = fmaf(Wh[3][1], hv1, Go);
            Gi = fmaf(Wh[0][2], hv2, Gi); Gf = fmaf(Wh[1][2], hv2, Gf);
            Gg = fmaf(Wh[2][2], hv2, Gg); Go = fmaf(Wh[3][2], hv2, Go);
            Gi = fmaf(Wh[0][3], hv3, Gi); Gf = fmaf(Wh[1][3], hv3, Gf);
            Gg = fmaf(Wh[2][3], hv3, Gg); Go = fmaf(Wh[3][3], hv3, Go);
            const float si = sigf(Gi);
            const float sf = sigf(Gf);
            const float tg = tanh_(Gg);
            const float so = sigf(Go);
            const float cn = fmaf(sf, c, si * tg);
            const float hn = so * tanh_(cn);
            const bool act = (unsigned)tc < (unsigned)S_LEN;
            c = act ? cn : c;
            h = act ? hn : h;
            // linear head (valid on L5 lanes; buffered, stored at chunk end)
            float s = h * regw;
            s += dppf<0xB1>(s);
            s += dppf<0x4E>(s);
            su[u] = s + regb;
            // publish for step n+2: feeders expose x[n+2], compute lanes h(t)
            h = isFeeder ? xu[u] : h;
            q1 = bpermf(bpaddr, h);
        }
        // ---- drain head outputs for this chunk ----
        if (isOut) {
            const int base = cc * CH - SKEW * (NL - 1);
#pragma unroll
            for (int u = 0; u < CH; ++u) {
                const int t = base + u;
                if (t >= 0 && t < S_LEN) out[(size_t)t * BATCH + b] = su[u];
            }
        }
        // ---- rotate prefetch buffer ----
#pragma unroll
        for (int u = 0; u < CH; ++u) xu[u] = xp[u];
    }
}

extern "C" void kernel_launch(void* const* d_in, const int* in_sizes, int n_in,
                              void* d_out, int out_size, void* d_ws, size_t ws_size,
                              hipStream_t stream) {
    const float* x     = (const float*)d_in[0];
    const float* w_ih  = (const float*)d_in[1];
    const float* w_hh  = (const float*)d_in[2];
    const float* b_ih  = (const float*)d_in[3];
    const float* b_hh  = (const float*)d_in[4];
    const float* reg_w = (const float*)d_in[5];
    const float* reg_b = (const float*)d_in[6];
    float* out = (float*)d_out;

    dim3 grid(BATCH / 2);   // 512 single-wave blocks, 2 batch elements each
    dim3 block(64);
    hipLaunchKernelGGL(lstm_wavepipe2, grid, block, 0, stream, x, w_ih, w_hh,
                       b_ih, b_hh, reg_w, reg_b, out);
}